// Round 10
// baseline (127.941 us; speedup 1.0000x reference)
//
#include <hip/hip_runtime.h>
#include <math.h>

#define NTOK 8192
#define NEMB 8192
#define DIM  256

typedef _Float16 f16x8 __attribute__((ext_vector_type(8)));   // 4 VGPRs
typedef _Float16 f16x4 __attribute__((ext_vector_type(4)));
typedef float    f32x4 __attribute__((ext_vector_type(4)));
typedef float    f32x16 __attribute__((ext_vector_type(16))); // 32x32 acc

// ---------------------------------------------------------------------------
// Kernel A: cast X and C to fp16 (RNE); fused exact fp32 ||c||^2 and ||x||^2
// (each wave covers exactly one 256-elem row). C-branch blocks x<8 zero
// counts; X-branch blocks x<8 init keys to u64-max.
__global__ __launch_bounds__(256) void convert_kernel(
        const float* __restrict__ X, const float* __restrict__ C,
        _Float16* __restrict__ Xh, _Float16* __restrict__ Ch,
        float* __restrict__ cnorm, float* __restrict__ xnorm,
        unsigned long long* __restrict__ keys, int* __restrict__ counts) {
    const bool isC = (blockIdx.y != 0);
    if (isC && blockIdx.x < 8) {
        ((int4*)counts)[blockIdx.x * 256 + threadIdx.x] = make_int4(0, 0, 0, 0);
    }
    if (!isC && blockIdx.x < 8) {
        int4 ff = make_int4(-1, -1, -1, -1);
        ((int4*)keys)[blockIdx.x * 512 + threadIdx.x * 2]     = ff;
        ((int4*)keys)[blockIdx.x * 512 + threadIdx.x * 2 + 1] = ff;
    }
    const float* src = isC ? C : X;
    _Float16* dst = isC ? Ch : Xh;
    size_t t = (size_t)blockIdx.x * 256 + threadIdx.x;   // one float4 per thread
    float4 x = *(const float4*)&src[t * 4];
    f16x4 h;
    h[0] = (_Float16)x.x; h[1] = (_Float16)x.y;
    h[2] = (_Float16)x.z; h[3] = (_Float16)x.w;
    *(f16x4*)&dst[t * 4] = h;
    float s = x.x * x.x + x.y * x.y + x.z * x.z + x.w * x.w;
    #pragma unroll
    for (int off = 32; off >= 1; off >>= 1) s += __shfl_xor(s, off);
    if ((threadIdx.x & 63) == 0) {
        if (isC) cnorm[t >> 6] = s; else xnorm[t >> 6] = s;
    }
}

// ---------------------------------------------------------------------------
// K32-chunk staging, 256x128 block tile (A=256 codes, B=128 tokens),
// 512 threads / 8 waves of 64x64 each (proven R5 structure, untouched).
// Swizzle s(row) = (row + (row>>2)) & 3 keeps frag ds_read_b128 at the
// port-minimum 8-lanes-per-bank-quad pattern.
__device__ __forceinline__ int swz(int row) { return (row + (row >> 2)) & 3; }

template<int N>
__device__ __forceinline__ void wait_vmcnt() {
    asm volatile("s_waitcnt vmcnt(%0)" :: "n"(N) : "memory");
}

// One K32 chunk: A = 1024 granules, B = 512 granules of 16B. With 512
// threads: 2 A + 1 B = 3 gload_lds/thread — vmcnt(3) relies on this.
__device__ __forceinline__ void stage_k32(
        const _Float16* __restrict__ Ag, const _Float16* __restrict__ Bg,
        _Float16* bufA, _Float16* bufB, int t) {
    #pragma unroll
    for (int c = 0; c < 2; ++c) {
        int gr  = c * 512 + t;
        int row = gr >> 2;
        int kg  = (gr & 3) ^ swz(row);
        __builtin_amdgcn_global_load_lds(
            (const __attribute__((address_space(1))) void*)(Ag + (size_t)row * DIM + kg * 8),
            (__attribute__((address_space(3))) void*)(bufA + (size_t)gr * 8), 16, 0, 0);
    }
    {
        int gr  = t;
        int row = gr >> 2;
        int kg  = (gr & 3) ^ swz(row);
        __builtin_amdgcn_global_load_lds(
            (const __attribute__((address_space(1))) void*)(Bg + (size_t)row * DIM + kg * 8),
            (__attribute__((address_space(3))) void*)(bufB + (size_t)gr * 8), 16, 0, 0);
    }
}

// 64x64 wave tile via v_mfma_f32_32x32x16_f16: 8 ds_read_b128 feed 8 MFMAs
// (was 16 MFMAs of 16x16x32). Same tile bytes/FLOP, same 64-reg acc, but
// the 32x32 pipe is ~20% more efficient (2495 vs 2075 TF ubench) and the
// instruction stream halves (fewer issue slots + lgkmcnt waits competing
// with staging). A-operand: row = lane&31, k = (lane>>5)*8 + e (same
// family construction as the verified working 16x16 frags: row = lane&15,
// k = (lane>>4)*8 + e). B mirrors with col = lane&31 = token.
__device__ __forceinline__ void compute_k32(
        const _Float16* Abuf, const _Float16* Bbuf, f32x16 (&acc)[2][2],
        int wm, int wn, int l31, int hi) {
    f16x8 af[2][2], bf_[2][2];          // [sub-tile][k-half]
    #pragma unroll
    for (int i = 0; i < 2; ++i)
        #pragma unroll
        for (int h = 0; h < 2; ++h) {
            int kg   = h * 2 + hi;      // k = h*16 + hi*8 .. +7
            int rowa = wm + i * 32 + l31;
            af[i][h] = *(const f16x8*)&Abuf[(rowa * 4 + (kg ^ swz(rowa))) * 8];
            int rowb = wn + i * 32 + l31;
            bf_[i][h] = *(const f16x8*)&Bbuf[(rowb * 4 + (kg ^ swz(rowb))) * 8];
        }
    __builtin_amdgcn_s_setprio(1);
    #pragma unroll
    for (int h = 0; h < 2; ++h)
        #pragma unroll
        for (int i = 0; i < 2; ++i)
            #pragma unroll
            for (int j = 0; j < 2; ++j)
                acc[i][j] = __builtin_amdgcn_mfma_f32_32x32x16_f16(
                    af[i][h], bf_[j][h], acc[i][j], 0, 0, 0);
    __builtin_amdgcn_s_setprio(0);
}

// ---------------------------------------------------------------------------
// Kernel B: fp16 distance GEMM (K=256, fp32 accum), A=codes (argmin over
// C/D rows). 256x128 block tile, 8 waves of 64x64, __launch_bounds__(512,4)
// -> 64 VGPR + 64 AGPR = 128/wave = exactly 4 waves/SIMD (2 blocks/CU,
// 32 waves/CU). Triple-buffered K32 ring (A 3x16KB + B 3x8KB = 72KB),
// single barrier + counted vmcnt(3) per phase. Epilogue: packed u64 key =
// bits(d+64)<<32 | code via atomicMin (order-isomorphic, tie -> lower code,
// order-independent => replay-safe). R8's in-kernel tail fusion reverted:
// measured worse than separate kernels (9.2 vs 7.6 us).
__global__ __launch_bounds__(512, 4) void mfma_argmin_kernel(
        const _Float16* __restrict__ Xh, const _Float16* __restrict__ Ch,
        const float* __restrict__ cnorm,
        unsigned long long* __restrict__ keys) {
    __shared__ __align__(16) _Float16 lds[36864];   // 72 KB
    _Float16* const ldsB = lds + 24576;             // B ring base (48 KB in)

    const int t = threadIdx.x;                      // 0..511
    const int wid = t >> 6, lane = t & 63;
    const int tb0 = blockIdx.x * 128;   // token block
    const int cb0 = blockIdx.y * 256;   // code block
    const int wm = (wid >> 1) * 64;     // wave's code offset (0/64/128/192)
    const int wn = (wid & 1) * 64;      // wave's token offset (0/64)
    const int l31 = lane & 31;
    const int hi  = lane >> 5;          // lane half (k-group / row+4 select)

    f32x16 acc[2][2];                   // [i=code sub][j=token sub] = 64 regs
    #pragma unroll
    for (int a = 0; a < 2; ++a)
        #pragma unroll
        for (int b = 0; b < 2; ++b) acc[a][b] = (f32x16)0.0f;

    const _Float16* Ag = Ch + (size_t)cb0 * DIM;   // codes
    const _Float16* Bg = Xh + (size_t)tb0 * DIM;   // tokens

    stage_k32(Ag,      Bg,      lds,        ldsB,        t);  // S(0)
    stage_k32(Ag + 32, Bg + 32, lds + 8192, ldsB + 4096, t);  // S(1)

    // Phase P: vmcnt(3) -> S(P) landed (S(P+1)'s 3 in flight); barrier ->
    // all waves' S(P) visible AND all done with compute(P-1) (last reader
    // of ring slot (P+2)%3); stage S(P+2); compute(P). sched_barrier(0)
    // pins ds_reads below the barrier (rule-#18 hazard class).
#define PHASE(P, WAITN)                                                       \
    do {                                                                      \
        wait_vmcnt<WAITN>();                                                  \
        __builtin_amdgcn_s_barrier();                                         \
        __builtin_amdgcn_sched_barrier(0);                                    \
        if ((P) + 2 < 8)                                                      \
            stage_k32(Ag + ((P) + 2) * 32, Bg + ((P) + 2) * 32,               \
                      lds + (((P) + 2) % 3) * 8192,                           \
                      ldsB + (((P) + 2) % 3) * 4096, t);                      \
        compute_k32(lds + ((P) % 3) * 8192, ldsB + ((P) % 3) * 4096,          \
                    acc, wm, wn, l31, hi);                                    \
        __builtin_amdgcn_sched_barrier(0);                                    \
    } while (0)

    PHASE(0, 3); PHASE(1, 3); PHASE(2, 3); PHASE(3, 3);
    PHASE(4, 3); PHASE(5, 3); PHASE(6, 3); PHASE(7, 0);
#undef PHASE

    // ---- epilogue: d = ||c||^2 - 2 c.x ; argmin over this block's 256
    // codes. 32x32 C/D layout (HW-verified m74/m101): token = lane&31,
    // code row = (reg&3) + 8*(reg>>2) + 4*hi (+ i*32 + wm). Each lane holds
    // 32 candidates per token sub-tile; lane-pair (l, l^32) covers all 64
    // rows of the wave tile -> one shfl_xor(32) combine. cnorm loaded
    // lazily per-i (16 regs peak, register-neutral). cmb = first 4 KB of
    // A-buf0: last read by compute(6), all waves passed the phase-7
    // barrier; compute(7) reads A-buf1/B-buf1 (disjoint).
    float* cmb_v = (float*)lds;                    // [128][4]
    int*   cmb_i = (int*)((float*)lds + 512);      // [128][4]

    float bv[2] = {1e30f, 1e30f};
    int   bi[2] = {0x7fffffff, 0x7fffffff};
    #pragma unroll
    for (int i = 0; i < 2; ++i) {
        f32x4 cq[4];
        #pragma unroll
        for (int q = 0; q < 4; ++q)
            cq[q] = *(const f32x4*)&cnorm[cb0 + wm + i * 32 + q * 8 + hi * 4];
        #pragma unroll
        for (int reg = 0; reg < 16; ++reg) {
            int row  = (reg & 3) + 8 * (reg >> 2) + 4 * hi;
            int code = cb0 + wm + i * 32 + row;
            float cn = cq[reg >> 2][reg & 3];
            #pragma unroll
            for (int j = 0; j < 2; ++j) {
                float d = fmaf(-2.0f, acc[i][j][reg], cn);
                if (d < bv[j] || (d == bv[j] && code < bi[j])) {
                    bv[j] = d; bi[j] = code;
                }
            }
        }
    }
    #pragma unroll
    for (int j = 0; j < 2; ++j) {
        float ov = __shfl_xor(bv[j], 32);
        int   oi = __shfl_xor(bi[j], 32);
        if (ov < bv[j] || (ov == bv[j] && oi < bi[j])) { bv[j] = ov; bi[j] = oi; }
        if (hi == 0) {
            int tl = wn + j * 32 + l31;             // token-local 0..127
            cmb_v[tl * 4 + (wid >> 1)] = bv[j];
            cmb_i[tl * 4 + (wid >> 1)] = bi[j];
        }
    }
    __syncthreads();
    if (t < 128) {
        float fv = cmb_v[t * 4]; int fi = cmb_i[t * 4];
        #pragma unroll
        for (int w = 1; w < 4; ++w) {
            float ov = cmb_v[t * 4 + w];
            int   oi = cmb_i[t * 4 + w];
            if (ov < fv || (ov == fv && oi < fi)) { fv = ov; fi = oi; }
        }
        unsigned long long key =
            ((unsigned long long)__builtin_bit_cast(unsigned, fv + 64.0f) << 32)
            | (unsigned)fi;
        atomicMin(&keys[tb0 + t], key);
    }
}

// ---------------------------------------------------------------------------
// Kernel C: unpack keys -> idx + distance, histogram via device atomics,
// gather C rows -> out, per-block loss partial (||x-c||^2 = xnorm + d) to
// psum. 256 blocks x 32 tokens.
__global__ __launch_bounds__(256) void gather_kernel(
        const float* __restrict__ C, const unsigned long long* __restrict__ keys,
        const float* __restrict__ xnorm, int* __restrict__ counts,
        float* __restrict__ out, float* __restrict__ psum) {
    __shared__ int idx_lds[32];
    const int m0 = blockIdx.x * 32;
    const int t = threadIdx.x;
    if (t < 32) {
        unsigned long long k = keys[m0 + t];
        int bi  = (int)(unsigned)k;
        float d = __builtin_bit_cast(float, (unsigned)(k >> 32)) - 64.0f;
        idx_lds[t] = bi;
        atomicAdd(&counts[bi], 1);
        float lt = d + xnorm[m0 + t];               // ||x - c||^2 for this token
        #pragma unroll
        for (int off = 1; off < 32; off <<= 1) lt += __shfl_xor(lt, off);
        if (t == 0) psum[blockIdx.x] = lt;
    }
    __syncthreads();
    const int wid = t >> 6, lane = t & 63;
    #pragma unroll
    for (int r = 0; r < 8; ++r) {
        int token = m0 + wid * 8 + r;
        int e = idx_lds[wid * 8 + r];
        float4 q = *(const float4*)&C[(size_t)e * DIM + lane * 4];
        *(float4*)&out[(size_t)token * DIM + lane * 4] = q;
    }
}

// ---------------------------------------------------------------------------
// Kernel D: entropy over the 8192-bin histogram + loss. 1024 threads x 8
// fully-unrolled loads -> 8 loads in flight/thread, 16 waves of TLP.
__global__ __launch_bounds__(1024) void finalize_kernel(
        const int* __restrict__ counts, const float* __restrict__ psum,
        float* __restrict__ out) {
    const int t = threadIdx.x;
    double local = 0.0;
    #pragma unroll
    for (int i = 0; i < 8; ++i) {
        int e = t + i * 1024;
        float p = (float)counts[e] * (1.0f / (float)NTOK);
        local += (double)(p * logf(p + 1e-10f));
    }
    float ls = (t < 256) ? psum[t] : 0.0f;   // 256 partial sums
    #pragma unroll
    for (int off = 32; off >= 1; off >>= 1) {
        local += __shfl_xor(local, off);
        ls    += __shfl_xor(ls, off);
    }
    __shared__ double she[16];
    __shared__ float  shs[16];
    int lane = t & 63, wid = t >> 6;
    if (lane == 0) { she[wid] = local; shs[wid] = ls; }
    __syncthreads();
    if (t == 0) {
        double ent = 0.0; float ssq = 0.0f;
        #pragma unroll
        for (int w = 0; w < 16; ++w) { ent += she[w]; ssq += shs[w]; }
        out[(size_t)NTOK * DIM]     = 1.25f * ssq / (float)((size_t)NTOK * DIM);
        out[(size_t)NTOK * DIM + 1] = expf((float)(-ent));
    }
}

// ---------------------------------------------------------------------------
extern "C" void kernel_launch(void* const* d_in, const int* in_sizes, int n_in,
                              void* d_out, int out_size, void* d_ws, size_t ws_size,
                              hipStream_t stream) {
    const float* X = (const float*)d_in[0];   // [32,256,256] fp32
    const float* C = (const float*)d_in[1];   // [8192,256]   fp32
    float* out = (float*)d_out;

    char* ws = (char*)d_ws;
    size_t o = 0;
    _Float16* Xh = (_Float16*)(ws + o); o += (size_t)NTOK * DIM * 2;
    _Float16* Ch = (_Float16*)(ws + o); o += (size_t)NEMB * DIM * 2;
    float* cnorm = (float*)(ws + o); o += (size_t)NEMB * 4;
    float* xnorm = (float*)(ws + o); o += (size_t)NTOK * 4;
    unsigned long long* keys = (unsigned long long*)(ws + o); o += (size_t)NTOK * 8;
    int* counts  = (int*)(ws + o);   o += (size_t)NEMB * 4;
    float* psum  = (float*)(ws + o);

    convert_kernel<<<dim3(NTOK * DIM / 4 / 256, 2), 256, 0, stream>>>(
        X, C, Xh, Ch, cnorm, xnorm, keys, counts);
    mfma_argmin_kernel<<<dim3(NTOK / 128, NEMB / 256), 512, 0, stream>>>(
        Xh, Ch, cnorm, keys);
    gather_kernel<<<256, 256, 0, stream>>>(
        C, keys, xnorm, counts, out, psum);
    finalize_kernel<<<1, 1024, 0, stream>>>(counts, psum, out);
}

// Round 11
// 119.468 us; speedup vs baseline: 1.0709x; 1.0709x over previous
//
#include <hip/hip_runtime.h>
#include <math.h>

#define NTOK 8192
#define NEMB 8192
#define DIM  256

typedef _Float16 f16x8 __attribute__((ext_vector_type(8)));   // 4 VGPRs
typedef _Float16 f16x4 __attribute__((ext_vector_type(4)));
typedef float    f32x4 __attribute__((ext_vector_type(4)));

// ---------------------------------------------------------------------------
// Kernel A: cast X and C to fp16 (RNE); fused exact fp32 ||c||^2 and ||x||^2
// (each wave covers exactly one 256-elem row). C-branch blocks x<8 zero
// counts; X-branch blocks x<8 init keys to u64-max.
__global__ __launch_bounds__(256) void convert_kernel(
        const float* __restrict__ X, const float* __restrict__ C,
        _Float16* __restrict__ Xh, _Float16* __restrict__ Ch,
        float* __restrict__ cnorm, float* __restrict__ xnorm,
        unsigned long long* __restrict__ keys, int* __restrict__ counts) {
    const bool isC = (blockIdx.y != 0);
    if (isC && blockIdx.x < 8) {
        ((int4*)counts)[blockIdx.x * 256 + threadIdx.x] = make_int4(0, 0, 0, 0);
    }
    if (!isC && blockIdx.x < 8) {
        int4 ff = make_int4(-1, -1, -1, -1);
        ((int4*)keys)[blockIdx.x * 512 + threadIdx.x * 2]     = ff;
        ((int4*)keys)[blockIdx.x * 512 + threadIdx.x * 2 + 1] = ff;
    }
    const float* src = isC ? C : X;
    _Float16* dst = isC ? Ch : Xh;
    size_t t = (size_t)blockIdx.x * 256 + threadIdx.x;   // one float4 per thread
    float4 x = *(const float4*)&src[t * 4];
    f16x4 h;
    h[0] = (_Float16)x.x; h[1] = (_Float16)x.y;
    h[2] = (_Float16)x.z; h[3] = (_Float16)x.w;
    *(f16x4*)&dst[t * 4] = h;
    float s = x.x * x.x + x.y * x.y + x.z * x.z + x.w * x.w;
    #pragma unroll
    for (int off = 32; off >= 1; off >>= 1) s += __shfl_xor(s, off);
    if ((threadIdx.x & 63) == 0) {
        if (isC) cnorm[t >> 6] = s; else xnorm[t >> 6] = s;
    }
}

// ---------------------------------------------------------------------------
// K32-chunk staging, 256x128 block tile (A=256 codes, B=128 tokens),
// 512 threads / 8 waves of 64x64 each (R5 structure — best measured:
// argmin 46.0 us. R10's 32x32-MFMA variant was conflict-free but SLOWER
// (51.9): LDS port conclusively not binding; 16x16 restored).
// Swizzle s(row) = (row + (row>>2)) & 3 keeps frag ds_read_b128 cheap.
__device__ __forceinline__ int swz(int row) { return (row + (row >> 2)) & 3; }

template<int N>
__device__ __forceinline__ void wait_vmcnt() {
    asm volatile("s_waitcnt vmcnt(%0)" :: "n"(N) : "memory");
}

// One K32 chunk: A = 1024 granules, B = 512 granules of 16B. With 512
// threads: 2 A + 1 B = 3 gload_lds/thread — vmcnt(3) relies on this.
__device__ __forceinline__ void stage_k32(
        const _Float16* __restrict__ Ag, const _Float16* __restrict__ Bg,
        _Float16* bufA, _Float16* bufB, int t) {
    #pragma unroll
    for (int c = 0; c < 2; ++c) {
        int gr  = c * 512 + t;
        int row = gr >> 2;
        int kg  = (gr & 3) ^ swz(row);
        __builtin_amdgcn_global_load_lds(
            (const __attribute__((address_space(1))) void*)(Ag + (size_t)row * DIM + kg * 8),
            (__attribute__((address_space(3))) void*)(bufA + (size_t)gr * 8), 16, 0, 0);
    }
    {
        int gr  = t;
        int row = gr >> 2;
        int kg  = (gr & 3) ^ swz(row);
        __builtin_amdgcn_global_load_lds(
            (const __attribute__((address_space(1))) void*)(Bg + (size_t)row * DIM + kg * 8),
            (__attribute__((address_space(3))) void*)(bufB + (size_t)gr * 8), 16, 0, 0);
    }
}

// 64x64 wave tile: 8 ds_read_b128 feed 16 MFMAs; acc = 64 VGPRs so
// 4 waves/SIMD fit (the R5 occupancy win).
__device__ __forceinline__ void compute_k32(
        const _Float16* Abuf, const _Float16* Bbuf, f32x4 (&acc)[4][4],
        int wm, int wn, int lrow, int g) {
    f16x8 af[4], bf_[4];
    #pragma unroll
    for (int i = 0; i < 4; ++i) {
        int row = wm + i * 16 + lrow;
        af[i] = *(const f16x8*)&Abuf[(row * 4 + (g ^ swz(row))) * 8];
    }
    #pragma unroll
    for (int j = 0; j < 4; ++j) {
        int row = wn + j * 16 + lrow;
        bf_[j] = *(const f16x8*)&Bbuf[(row * 4 + (g ^ swz(row))) * 8];
    }
    __builtin_amdgcn_s_setprio(1);
    #pragma unroll
    for (int i = 0; i < 4; ++i)
        #pragma unroll
        for (int j = 0; j < 4; ++j)
            acc[i][j] = __builtin_amdgcn_mfma_f32_16x16x32_f16(
                af[i], bf_[j], acc[i][j], 0, 0, 0);
    __builtin_amdgcn_s_setprio(0);
}

// ---------------------------------------------------------------------------
// Kernel B: fp16 distance GEMM (K=256, fp32 accum), A=codes (argmin over
// C/D rows). 256x128 block tile, 8 waves of 64x64, __launch_bounds__(512,4)
// -> 4 waves/SIMD, 2 blocks/CU. Triple-buffered K32 ring (72KB), single
// barrier + counted vmcnt(3) per phase.
// NEW vs R5: XCD-aware block swizzle. Default dispatch round-robins the
// 2048 blocks over 8 XCDs -> each 4MB XCD-L2 thrashes on BOTH the 4MB Ch
// and 4MB Xh panels (measured FETCH 18.6MB vs 8MB working set = 2.3x
// refetch). Bijective remap (2048%8==0): flat=(y*64+x),
// swz=(flat%8)*256+flat/8 -> each XCD owns 4 contiguous code-rows x all
// token columns (~0.5MB Ch panel resident + Xh streamed). Kernel is
// latency-exposed (nothing >40% busy), so L2-miss->hit on the staging
// path directly shrinks the exposed window.
// Epilogue: packed u64 key = bits(d+64)<<32 | code via atomicMin
// (order-isomorphic, tie -> lower code, order-independent => replay-safe).
__global__ __launch_bounds__(512, 4) void mfma_argmin_kernel(
        const _Float16* __restrict__ Xh, const _Float16* __restrict__ Ch,
        const float* __restrict__ cnorm,
        unsigned long long* __restrict__ keys) {
    __shared__ __align__(16) _Float16 lds[36864];   // 72 KB
    _Float16* const ldsB = lds + 24576;             // B ring base (48 KB in)

    const int t = threadIdx.x;                      // 0..511
    const int wid = t >> 6, lane = t & 63;
    // XCD-aware swizzle: 2048 blocks -> 8 XCD chunks of 256.
    const int flat = blockIdx.y * 64 + blockIdx.x;
    const int swzf = (flat & 7) * 256 + (flat >> 3);
    const int tb0 = (swzf & 63) * 128;  // token block
    const int cb0 = (swzf >> 6) * 256;  // code block
    const int wm = (wid >> 1) * 64;     // wave's code offset (0/64/128/192)
    const int wn = (wid & 1) * 64;      // wave's token offset (0/64)
    const int lrow = lane & 15;
    const int g = lane >> 4;            // quad

    f32x4 acc[4][4];                    // [tm=codes][tn=tokens] = 64 VGPRs
    #pragma unroll
    for (int a = 0; a < 4; ++a)
        #pragma unroll
        for (int b = 0; b < 4; ++b) acc[a][b] = (f32x4)0.0f;

    const _Float16* Ag = Ch + (size_t)cb0 * DIM;   // codes
    const _Float16* Bg = Xh + (size_t)tb0 * DIM;   // tokens

    stage_k32(Ag,      Bg,      lds,        ldsB,        t);  // S(0)
    stage_k32(Ag + 32, Bg + 32, lds + 8192, ldsB + 4096, t);  // S(1)

    // Phase P: vmcnt(3) -> S(P) landed (S(P+1)'s 3 in flight); barrier ->
    // all waves' S(P) visible AND all done with compute(P-1) (last reader
    // of ring slot (P+2)%3); stage S(P+2); compute(P). sched_barrier(0)
    // pins ds_reads below the barrier (rule-#18 hazard class).
#define PHASE(P, WAITN)                                                       \
    do {                                                                      \
        wait_vmcnt<WAITN>();                                                  \
        __builtin_amdgcn_s_barrier();                                         \
        __builtin_amdgcn_sched_barrier(0);                                    \
        if ((P) + 2 < 8)                                                      \
            stage_k32(Ag + ((P) + 2) * 32, Bg + ((P) + 2) * 32,               \
                      lds + (((P) + 2) % 3) * 8192,                           \
                      ldsB + (((P) + 2) % 3) * 4096, t);                      \
        compute_k32(lds + ((P) % 3) * 8192, ldsB + ((P) % 3) * 4096,          \
                    acc, wm, wn, lrow, g);                                    \
        __builtin_amdgcn_sched_barrier(0);                                    \
    } while (0)

    PHASE(0, 3); PHASE(1, 3); PHASE(2, 3); PHASE(3, 3);
    PHASE(4, 3); PHASE(5, 3); PHASE(6, 3); PHASE(7, 0);
#undef PHASE

    // ---- epilogue: d = ||c||^2 - 2 c.x ; argmin over this block's 256
    // codes. cmb = first 4 KB of A-buf0: last read by compute(6), all waves
    // passed the phase-7 barrier; compute(7) reads A-buf1/B-buf1 (disjoint).
    float cn[16];
    #pragma unroll
    for (int tm = 0; tm < 4; ++tm)
        #pragma unroll
        for (int reg = 0; reg < 4; ++reg)
            cn[tm * 4 + reg] = cnorm[cb0 + wm + tm * 16 + g * 4 + reg];

    float* cmb_v = (float*)lds;                    // [128][4]
    int*   cmb_i = (int*)((float*)lds + 512);      // [128][4]

    #pragma unroll
    for (int tn = 0; tn < 4; ++tn) {
        float bv = 1e30f; int bi = 0x7fffffff;
        #pragma unroll
        for (int tm = 0; tm < 4; ++tm) {
            #pragma unroll
            for (int reg = 0; reg < 4; ++reg) {
                float d = fmaf(-2.0f, acc[tm][tn][reg], cn[tm * 4 + reg]);
                int code = cb0 + wm + tm * 16 + g * 4 + reg;  // ascending -> strict <
                if (d < bv) { bv = d; bi = code; }
            }
        }
        #pragma unroll
        for (int off = 16; off <= 32; off <<= 1) {  // reduce over the 4 quads
            float ov = __shfl_xor(bv, off);
            int   oi = __shfl_xor(bi, off);
            if (ov < bv || (ov == bv && oi < bi)) { bv = ov; bi = oi; }
        }
        if (g == 0) {
            int tl = wn + tn * 16 + lrow;           // token-local 0..127
            cmb_v[tl * 4 + (wid >> 1)] = bv;
            cmb_i[tl * 4 + (wid >> 1)] = bi;
        }
    }
    __syncthreads();
    if (t < 128) {
        float bv = cmb_v[t * 4]; int bi = cmb_i[t * 4];
        #pragma unroll
        for (int w = 1; w < 4; ++w) {
            float ov = cmb_v[t * 4 + w];
            int   oi = cmb_i[t * 4 + w];
            if (ov < bv || (ov == bv && oi < bi)) { bv = ov; bi = oi; }
        }
        unsigned long long key =
            ((unsigned long long)__builtin_bit_cast(unsigned, bv + 64.0f) << 32)
            | (unsigned)bi;
        atomicMin(&keys[tb0 + t], key);
    }
}

// ---------------------------------------------------------------------------
// Kernel C: unpack keys -> idx + distance, histogram via device atomics,
// gather C rows -> out, per-block loss partial (||x-c||^2 = xnorm + d) to
// psum. 256 blocks x 32 tokens.
__global__ __launch_bounds__(256) void gather_kernel(
        const float* __restrict__ C, const unsigned long long* __restrict__ keys,
        const float* __restrict__ xnorm, int* __restrict__ counts,
        float* __restrict__ out, float* __restrict__ psum) {
    __shared__ int idx_lds[32];
    const int m0 = blockIdx.x * 32;
    const int t = threadIdx.x;
    if (t < 32) {
        unsigned long long k = keys[m0 + t];
        int bi  = (int)(unsigned)k;
        float d = __builtin_bit_cast(float, (unsigned)(k >> 32)) - 64.0f;
        idx_lds[t] = bi;
        atomicAdd(&counts[bi], 1);
        float lt = d + xnorm[m0 + t];               // ||x - c||^2 for this token
        #pragma unroll
        for (int off = 1; off < 32; off <<= 1) lt += __shfl_xor(lt, off);
        if (t == 0) psum[blockIdx.x] = lt;
    }
    __syncthreads();
    const int wid = t >> 6, lane = t & 63;
    #pragma unroll
    for (int r = 0; r < 8; ++r) {
        int token = m0 + wid * 8 + r;
        int e = idx_lds[wid * 8 + r];
        float4 q = *(const float4*)&C[(size_t)e * DIM + lane * 4];
        *(float4*)&out[(size_t)token * DIM + lane * 4] = q;
    }
}

// ---------------------------------------------------------------------------
// Kernel D: entropy over the 8192-bin histogram + loss. 1024 threads x 8
// fully-unrolled loads -> 8 loads in flight/thread, 16 waves of TLP.
__global__ __launch_bounds__(1024) void finalize_kernel(
        const int* __restrict__ counts, const float* __restrict__ psum,
        float* __restrict__ out) {
    const int t = threadIdx.x;
    double local = 0.0;
    #pragma unroll
    for (int i = 0; i < 8; ++i) {
        int e = t + i * 1024;
        float p = (float)counts[e] * (1.0f / (float)NTOK);
        local += (double)(p * logf(p + 1e-10f));
    }
    float ls = (t < 256) ? psum[t] : 0.0f;   // 256 partial sums
    #pragma unroll
    for (int off = 32; off >= 1; off >>= 1) {
        local += __shfl_xor(local, off);
        ls    += __shfl_xor(ls, off);
    }
    __shared__ double she[16];
    __shared__ float  shs[16];
    int lane = t & 63, wid = t >> 6;
    if (lane == 0) { she[wid] = local; shs[wid] = ls; }
    __syncthreads();
    if (t == 0) {
        double ent = 0.0; float ssq = 0.0f;
        #pragma unroll
        for (int w = 0; w < 16; ++w) { ent += she[w]; ssq += shs[w]; }
        out[(size_t)NTOK * DIM]     = 1.25f * ssq / (float)((size_t)NTOK * DIM);
        out[(size_t)NTOK * DIM + 1] = expf((float)(-ent));
    }
}

// ---------------------------------------------------------------------------
extern "C" void kernel_launch(void* const* d_in, const int* in_sizes, int n_in,
                              void* d_out, int out_size, void* d_ws, size_t ws_size,
                              hipStream_t stream) {
    const float* X = (const float*)d_in[0];   // [32,256,256] fp32
    const float* C = (const float*)d_in[1];   // [8192,256]   fp32
    float* out = (float*)d_out;

    char* ws = (char*)d_ws;
    size_t o = 0;
    _Float16* Xh = (_Float16*)(ws + o); o += (size_t)NTOK * DIM * 2;
    _Float16* Ch = (_Float16*)(ws + o); o += (size_t)NEMB * DIM * 2;
    float* cnorm = (float*)(ws + o); o += (size_t)NEMB * 4;
    float* xnorm = (float*)(ws + o); o += (size_t)NTOK * 4;
    unsigned long long* keys = (unsigned long long*)(ws + o); o += (size_t)NTOK * 8;
    int* counts  = (int*)(ws + o);   o += (size_t)NEMB * 4;
    float* psum  = (float*)(ws + o);

    convert_kernel<<<dim3(NTOK * DIM / 4 / 256, 2), 256, 0, stream>>>(
        X, C, Xh, Ch, cnorm, xnorm, keys, counts);
    mfma_argmin_kernel<<<dim3(NTOK / 128, NEMB / 256), 512, 0, stream>>>(
        Xh, Ch, cnorm, keys);
    gather_kernel<<<256, 256, 0, stream>>>(
        C, keys, xnorm, counts, out, psum);
    finalize_kernel<<<1, 1024, 0, stream>>>(counts, psum, out);
}

// Round 12
// 117.239 us; speedup vs baseline: 1.0913x; 1.0190x over previous
//
#include <hip/hip_runtime.h>
#include <math.h>

#define NTOK 8192
#define NEMB 8192
#define DIM  256

typedef _Float16 f16x8 __attribute__((ext_vector_type(8)));   // 4 VGPRs
typedef _Float16 f16x4 __attribute__((ext_vector_type(4)));
typedef float    f32x4 __attribute__((ext_vector_type(4)));

// ---------------------------------------------------------------------------
// Kernel A: cast X and C to fp16 (RNE); fused exact fp32 ||c||^2 and ||x||^2
// (each wave covers exactly one 256-elem row). C-branch blocks x<8 zero
// counts; X-branch blocks x<8 init keys to u64-max.
__global__ __launch_bounds__(256) void convert_kernel(
        const float* __restrict__ X, const float* __restrict__ C,
        _Float16* __restrict__ Xh, _Float16* __restrict__ Ch,
        float* __restrict__ cnorm, float* __restrict__ xnorm,
        unsigned long long* __restrict__ keys, int* __restrict__ counts) {
    const bool isC = (blockIdx.y != 0);
    if (isC && blockIdx.x < 8) {
        ((int4*)counts)[blockIdx.x * 256 + threadIdx.x] = make_int4(0, 0, 0, 0);
    }
    if (!isC && blockIdx.x < 8) {
        int4 ff = make_int4(-1, -1, -1, -1);
        ((int4*)keys)[blockIdx.x * 512 + threadIdx.x * 2]     = ff;
        ((int4*)keys)[blockIdx.x * 512 + threadIdx.x * 2 + 1] = ff;
    }
    const float* src = isC ? C : X;
    _Float16* dst = isC ? Ch : Xh;
    size_t t = (size_t)blockIdx.x * 256 + threadIdx.x;   // one float4 per thread
    float4 x = *(const float4*)&src[t * 4];
    f16x4 h;
    h[0] = (_Float16)x.x; h[1] = (_Float16)x.y;
    h[2] = (_Float16)x.z; h[3] = (_Float16)x.w;
    *(f16x4*)&dst[t * 4] = h;
    float s = x.x * x.x + x.y * x.y + x.z * x.z + x.w * x.w;
    #pragma unroll
    for (int off = 32; off >= 1; off >>= 1) s += __shfl_xor(s, off);
    if ((threadIdx.x & 63) == 0) {
        if (isC) cnorm[t >> 6] = s; else xnorm[t >> 6] = s;
    }
}

// ---------------------------------------------------------------------------
// K32-chunk staging, 256x128 block tile (A=256 codes, B=128 tokens),
// 512 threads / 8 waves of 64x64 each (R5 structure — best measured:
// argmin 46.0 us). Session ledger (counter-evidenced): LDS port not
// binding (R4 B-in-reg −21%, R10 conflict-free 32x32 −13%); barrier
// count not binding (R2 halving = −1%); launch gaps not the residue
// (R8 fusion = null); XCD swizzle doubles FETCH and regresses (R11);
// occupancy hard-capped at 4 waves/SIMD (acc 64 + frags > 64 regs).
// Swizzle s(row) = (row + (row>>2)) & 3 keeps frag ds_read_b128 cheap.
__device__ __forceinline__ int swz(int row) { return (row + (row >> 2)) & 3; }

template<int N>
__device__ __forceinline__ void wait_vmcnt() {
    asm volatile("s_waitcnt vmcnt(%0)" :: "n"(N) : "memory");
}

// One K32 chunk: A = 1024 granules, B = 512 granules of 16B. With 512
// threads: 2 A + 1 B = 3 gload_lds/thread — vmcnt(3) relies on this.
__device__ __forceinline__ void stage_k32(
        const _Float16* __restrict__ Ag, const _Float16* __restrict__ Bg,
        _Float16* bufA, _Float16* bufB, int t) {
    #pragma unroll
    for (int c = 0; c < 2; ++c) {
        int gr  = c * 512 + t;
        int row = gr >> 2;
        int kg  = (gr & 3) ^ swz(row);
        __builtin_amdgcn_global_load_lds(
            (const __attribute__((address_space(1))) void*)(Ag + (size_t)row * DIM + kg * 8),
            (__attribute__((address_space(3))) void*)(bufA + (size_t)gr * 8), 16, 0, 0);
    }
    {
        int gr  = t;
        int row = gr >> 2;
        int kg  = (gr & 3) ^ swz(row);
        __builtin_amdgcn_global_load_lds(
            (const __attribute__((address_space(1))) void*)(Bg + (size_t)row * DIM + kg * 8),
            (__attribute__((address_space(3))) void*)(bufB + (size_t)gr * 8), 16, 0, 0);
    }
}

// 64x64 wave tile: 8 ds_read_b128 feed 16 MFMAs; acc = 64 VGPRs so
// 4 waves/SIMD fit (the R5 occupancy win).
__device__ __forceinline__ void compute_k32(
        const _Float16* Abuf, const _Float16* Bbuf, f32x4 (&acc)[4][4],
        int wm, int wn, int lrow, int g) {
    f16x8 af[4], bf_[4];
    #pragma unroll
    for (int i = 0; i < 4; ++i) {
        int row = wm + i * 16 + lrow;
        af[i] = *(const f16x8*)&Abuf[(row * 4 + (g ^ swz(row))) * 8];
    }
    #pragma unroll
    for (int j = 0; j < 4; ++j) {
        int row = wn + j * 16 + lrow;
        bf_[j] = *(const f16x8*)&Bbuf[(row * 4 + (g ^ swz(row))) * 8];
    }
    __builtin_amdgcn_s_setprio(1);
    #pragma unroll
    for (int i = 0; i < 4; ++i)
        #pragma unroll
        for (int j = 0; j < 4; ++j)
            acc[i][j] = __builtin_amdgcn_mfma_f32_16x16x32_f16(
                af[i], bf_[j], acc[i][j], 0, 0, 0);
    __builtin_amdgcn_s_setprio(0);
}

// ---------------------------------------------------------------------------
// Kernel B: fp16 distance GEMM (K=256, fp32 accum), A=codes (argmin over
// C/D rows). 256x128 block tile, 8 waves of 64x64, __launch_bounds__(512,4)
// -> 64 VGPR + 64 AGPR = 128/wave = exactly 4 waves/SIMD (2 blocks/CU,
// 32 waves/CU). Triple-buffered K32 ring (A 3x16KB + B 3x8KB = 72KB),
// single barrier + counted vmcnt(3) per phase (stage(P+1)'s 3 loads stay
// in flight across the barrier; stage(P+2) issued after it -> every chunk
// gets two phases to land). Default block order (R11: XCD swizzle doubles
// FETCH — round-robin + L3 beats static partitioning here).
// Epilogue: packed u64 key = bits(d+64)<<32 | code via atomicMin
// (order-isomorphic, tie -> lower code, order-independent => replay-safe).
__global__ __launch_bounds__(512, 4) void mfma_argmin_kernel(
        const _Float16* __restrict__ Xh, const _Float16* __restrict__ Ch,
        const float* __restrict__ cnorm,
        unsigned long long* __restrict__ keys) {
    __shared__ __align__(16) _Float16 lds[36864];   // 72 KB
    _Float16* const ldsB = lds + 24576;             // B ring base (48 KB in)

    const int t = threadIdx.x;                      // 0..511
    const int wid = t >> 6, lane = t & 63;
    const int tb0 = blockIdx.x * 128;   // token block
    const int cb0 = blockIdx.y * 256;   // code block
    const int wm = (wid >> 1) * 64;     // wave's code offset (0/64/128/192)
    const int wn = (wid & 1) * 64;      // wave's token offset (0/64)
    const int lrow = lane & 15;
    const int g = lane >> 4;            // quad

    f32x4 acc[4][4];                    // [tm=codes][tn=tokens] = 64 VGPRs
    #pragma unroll
    for (int a = 0; a < 4; ++a)
        #pragma unroll
        for (int b = 0; b < 4; ++b) acc[a][b] = (f32x4)0.0f;

    const _Float16* Ag = Ch + (size_t)cb0 * DIM;   // codes
    const _Float16* Bg = Xh + (size_t)tb0 * DIM;   // tokens

    stage_k32(Ag,      Bg,      lds,        ldsB,        t);  // S(0)
    stage_k32(Ag + 32, Bg + 32, lds + 8192, ldsB + 4096, t);  // S(1)

    // Phase P: vmcnt(3) -> S(P) landed (S(P+1)'s 3 in flight); barrier ->
    // all waves' S(P) visible AND all done with compute(P-1) (last reader
    // of ring slot (P+2)%3); stage S(P+2); compute(P). sched_barrier(0)
    // pins ds_reads below the barrier (rule-#18 hazard class).
#define PHASE(P, WAITN)                                                       \
    do {                                                                      \
        wait_vmcnt<WAITN>();                                                  \
        __builtin_amdgcn_s_barrier();                                         \
        __builtin_amdgcn_sched_barrier(0);                                    \
        if ((P) + 2 < 8)                                                      \
            stage_k32(Ag + ((P) + 2) * 32, Bg + ((P) + 2) * 32,               \
                      lds + (((P) + 2) % 3) * 8192,                           \
                      ldsB + (((P) + 2) % 3) * 4096, t);                      \
        compute_k32(lds + ((P) % 3) * 8192, ldsB + ((P) % 3) * 4096,          \
                    acc, wm, wn, lrow, g);                                    \
        __builtin_amdgcn_sched_barrier(0);                                    \
    } while (0)

    PHASE(0, 3); PHASE(1, 3); PHASE(2, 3); PHASE(3, 3);
    PHASE(4, 3); PHASE(5, 3); PHASE(6, 3); PHASE(7, 0);
#undef PHASE

    // ---- epilogue: d = ||c||^2 - 2 c.x ; argmin over this block's 256
    // codes. cmb = first 4 KB of A-buf0: last read by compute(6), all waves
    // passed the phase-7 barrier; compute(7) reads A-buf1/B-buf1 (disjoint).
    float cn[16];
    #pragma unroll
    for (int tm = 0; tm < 4; ++tm)
        #pragma unroll
        for (int reg = 0; reg < 4; ++reg)
            cn[tm * 4 + reg] = cnorm[cb0 + wm + tm * 16 + g * 4 + reg];

    float* cmb_v = (float*)lds;                    // [128][4]
    int*   cmb_i = (int*)((float*)lds + 512);      // [128][4]

    #pragma unroll
    for (int tn = 0; tn < 4; ++tn) {
        float bv = 1e30f; int bi = 0x7fffffff;
        #pragma unroll
        for (int tm = 0; tm < 4; ++tm) {
            #pragma unroll
            for (int reg = 0; reg < 4; ++reg) {
                float d = fmaf(-2.0f, acc[tm][tn][reg], cn[tm * 4 + reg]);
                int code = cb0 + wm + tm * 16 + g * 4 + reg;  // ascending -> strict <
                if (d < bv) { bv = d; bi = code; }
            }
        }
        #pragma unroll
        for (int off = 16; off <= 32; off <<= 1) {  // reduce over the 4 quads
            float ov = __shfl_xor(bv, off);
            int   oi = __shfl_xor(bi, off);
            if (ov < bv || (ov == bv && oi < bi)) { bv = ov; bi = oi; }
        }
        if (g == 0) {
            int tl = wn + tn * 16 + lrow;           // token-local 0..127
            cmb_v[tl * 4 + (wid >> 1)] = bv;
            cmb_i[tl * 4 + (wid >> 1)] = bi;
        }
    }
    __syncthreads();
    if (t < 128) {
        float bv = cmb_v[t * 4]; int bi = cmb_i[t * 4];
        #pragma unroll
        for (int w = 1; w < 4; ++w) {
            float ov = cmb_v[t * 4 + w];
            int   oi = cmb_i[t * 4 + w];
            if (ov < bv || (ov == bv && oi < bi)) { bv = ov; bi = oi; }
        }
        unsigned long long key =
            ((unsigned long long)__builtin_bit_cast(unsigned, bv + 64.0f) << 32)
            | (unsigned)bi;
        atomicMin(&keys[tb0 + t], key);
    }
}

// ---------------------------------------------------------------------------
// Kernel C: unpack keys -> idx + distance, histogram via device atomics,
// gather C rows -> out, per-block loss partial (||x-c||^2 = xnorm + d) to
// psum. 256 blocks x 32 tokens.
__global__ __launch_bounds__(256) void gather_kernel(
        const float* __restrict__ C, const unsigned long long* __restrict__ keys,
        const float* __restrict__ xnorm, int* __restrict__ counts,
        float* __restrict__ out, float* __restrict__ psum) {
    __shared__ int idx_lds[32];
    const int m0 = blockIdx.x * 32;
    const int t = threadIdx.x;
    if (t < 32) {
        unsigned long long k = keys[m0 + t];
        int bi  = (int)(unsigned)k;
        float d = __builtin_bit_cast(float, (unsigned)(k >> 32)) - 64.0f;
        idx_lds[t] = bi;
        atomicAdd(&counts[bi], 1);
        float lt = d + xnorm[m0 + t];               // ||x - c||^2 for this token
        #pragma unroll
        for (int off = 1; off < 32; off <<= 1) lt += __shfl_xor(lt, off);
        if (t == 0) psum[blockIdx.x] = lt;
    }
    __syncthreads();
    const int wid = t >> 6, lane = t & 63;
    #pragma unroll
    for (int r = 0; r < 8; ++r) {
        int token = m0 + wid * 8 + r;
        int e = idx_lds[wid * 8 + r];
        float4 q = *(const float4*)&C[(size_t)e * DIM + lane * 4];
        *(float4*)&out[(size_t)token * DIM + lane * 4] = q;
    }
}

// ---------------------------------------------------------------------------
// Kernel D: entropy over the 8192-bin histogram + loss. 1024 threads x 8
// fully-unrolled loads -> 8 loads in flight/thread, 16 waves of TLP.
__global__ __launch_bounds__(1024) void finalize_kernel(
        const int* __restrict__ counts, const float* __restrict__ psum,
        float* __restrict__ out) {
    const int t = threadIdx.x;
    double local = 0.0;
    #pragma unroll
    for (int i = 0; i < 8; ++i) {
        int e = t + i * 1024;
        float p = (float)counts[e] * (1.0f / (float)NTOK);
        local += (double)(p * logf(p + 1e-10f));
    }
    float ls = (t < 256) ? psum[t] : 0.0f;   // 256 partial sums
    #pragma unroll
    for (int off = 32; off >= 1; off >>= 1) {
        local += __shfl_xor(local, off);
        ls    += __shfl_xor(ls, off);
    }
    __shared__ double she[16];
    __shared__ float  shs[16];
    int lane = t & 63, wid = t >> 6;
    if (lane == 0) { she[wid] = local; shs[wid] = ls; }
    __syncthreads();
    if (t == 0) {
        double ent = 0.0; float ssq = 0.0f;
        #pragma unroll
        for (int w = 0; w < 16; ++w) { ent += she[w]; ssq += shs[w]; }
        out[(size_t)NTOK * DIM]     = 1.25f * ssq / (float)((size_t)NTOK * DIM);
        out[(size_t)NTOK * DIM + 1] = expf((float)(-ent));
    }
}

// ---------------------------------------------------------------------------
extern "C" void kernel_launch(void* const* d_in, const int* in_sizes, int n_in,
                              void* d_out, int out_size, void* d_ws, size_t ws_size,
                              hipStream_t stream) {
    const float* X = (const float*)d_in[0];   // [32,256,256] fp32
    const float* C = (const float*)d_in[1];   // [8192,256]   fp32
    float* out = (float*)d_out;

    char* ws = (char*)d_ws;
    size_t o = 0;
    _Float16* Xh = (_Float16*)(ws + o); o += (size_t)NTOK * DIM * 2;
    _Float16* Ch = (_Float16*)(ws + o); o += (size_t)NEMB * DIM * 2;
    float* cnorm = (float*)(ws + o); o += (size_t)NEMB * 4;
    float* xnorm = (float*)(ws + o); o += (size_t)NTOK * 4;
    unsigned long long* keys = (unsigned long long*)(ws + o); o += (size_t)NTOK * 8;
    int* counts  = (int*)(ws + o);   o += (size_t)NEMB * 4;
    float* psum  = (float*)(ws + o);

    convert_kernel<<<dim3(NTOK * DIM / 4 / 256, 2), 256, 0, stream>>>(
        X, C, Xh, Ch, cnorm, xnorm, keys, counts);
    mfma_argmin_kernel<<<dim3(NTOK / 128, NEMB / 256), 512, 0, stream>>>(
        Xh, Ch, cnorm, keys);
    gather_kernel<<<256, 256, 0, stream>>>(
        C, keys, xnorm, counts, out, psum);
    finalize_kernel<<<1, 1024, 0, stream>>>(counts, psum, out);
}